// Round 1
// baseline (77.760 us; speedup 1.0000x reference)
//
#include <hip/hip_runtime.h>

typedef short short8 __attribute__((ext_vector_type(8)));
typedef float f32x4 __attribute__((ext_vector_type(4)));
typedef unsigned short u16;
typedef u16 u16x4 __attribute__((ext_vector_type(4)));

// fp32 -> bf16 bits, round-to-nearest-even
__device__ __forceinline__ u16 f2bf(float f) {
  unsigned u = __builtin_bit_cast(unsigned, f);
  u = (u + 0x7FFFu + ((u >> 16) & 1u)) >> 16;
  return (u16)u;
}

__device__ __forceinline__ f32x4 mfma16(short8 a, short8 b, f32x4 c) {
  return __builtin_amdgcn_mfma_f32_16x16x32_bf16(a, b, c, 0, 0, 0);
}

__device__ __forceinline__ short8 pack8(float4 a, float4 b) {
  short8 v;
  v[0] = (short)f2bf(a.x); v[1] = (short)f2bf(a.y);
  v[2] = (short)f2bf(a.z); v[3] = (short)f2bf(a.w);
  v[4] = (short)f2bf(b.x); v[5] = (short)f2bf(b.y);
  v[6] = (short)f2bf(b.z); v[7] = (short)f2bf(b.w);
  return v;
}

// ---------------------------------------------------------------------------
// Projection: q = x@Wq^T, k = x@Wk^T, v = x@Wv^T   (bf16 outputs)
// x: [16384,1024] f32. W*: [64,1024] f32 (already B^T form).
// qw,kw: [8][2048][64] bf16 row-major.  vtw: [8][64][2048] bf16 (V transposed).
// BM=64 rows/block, BN=192 (all three heads), BK=64, 8 waves (2 row x 4 col).
// ---------------------------------------------------------------------------
__global__ __launch_bounds__(512) void proj_kernel(
    const float* __restrict__ x, const float* __restrict__ Wq,
    const float* __restrict__ Wk, const float* __restrict__ Wv,
    u16* __restrict__ qw, u16* __restrict__ kw, u16* __restrict__ vtw)
{
  const int tid  = threadIdx.x;
  const int row0 = blockIdx.x * 64;
  const int lane = tid & 63;
  const int w    = tid >> 6;
  const int lr   = lane & 15, lg = lane >> 4;
  const int wr   = w >> 2, wc = w & 3;    // 2x4 wave grid: 32 rows x 48 cols each

  __shared__ u16 lA[64 * 64];    // 8 KB  (XOR-swizzled)
  __shared__ u16 lW[192 * 64];   // 24 KB (XOR-swizzled)

  const f32x4 vzero = {0.f, 0.f, 0.f, 0.f};
  f32x4 acc[2][3];
#pragma unroll
  for (int m = 0; m < 2; ++m)
#pragma unroll
    for (int c = 0; c < 3; ++c) acc[m][c] = vzero;

  const int srow = tid >> 3;          // 0..63
  const int scol = (tid & 7) * 8;     // 0..56
  const float* xp  = x  + (size_t)(row0 + srow) * 1024 + scol;
  const float* wp0 = Wq + (size_t)srow * 1024 + scol;
  const float* wp1 = Wk + (size_t)srow * 1024 + scol;
  const float* wp2 = Wv + (size_t)srow * 1024 + scol;
  const int sIdx = srow * 64 + (scol ^ ((srow & 7) << 3));

  for (int k0 = 0; k0 < 1024; k0 += 64) {
    float4 a0 = *(const float4*)(xp + k0);
    float4 a1 = *(const float4*)(xp + k0 + 4);
    float4 b0 = *(const float4*)(wp0 + k0);
    float4 b1 = *(const float4*)(wp0 + k0 + 4);
    float4 c0 = *(const float4*)(wp1 + k0);
    float4 c1 = *(const float4*)(wp1 + k0 + 4);
    float4 d0 = *(const float4*)(wp2 + k0);
    float4 d1 = *(const float4*)(wp2 + k0 + 4);
    __syncthreads();
    *(short8*)&lA[sIdx]            = pack8(a0, a1);
    *(short8*)&lW[sIdx]            = pack8(b0, b1);   // rows   0..63  = Wq
    *(short8*)&lW[sIdx + 64 * 64]  = pack8(c0, c1);   // rows  64..127 = Wk
    *(short8*)&lW[sIdx + 128 * 64] = pack8(d0, d1);   // rows 128..191 = Wv
    __syncthreads();

    short8 af[2][2], wf[3][2];
#pragma unroll
    for (int m = 0; m < 2; ++m) {
      const int ar = wr * 32 + m * 16 + lr;
#pragma unroll
      for (int ks = 0; ks < 2; ++ks)
        af[m][ks] = *(const short8*)&lA[ar * 64 + (((ks << 5) | (lg << 3)) ^ ((ar & 7) << 3))];
    }
#pragma unroll
    for (int c = 0; c < 3; ++c) {
      const int nr = wc * 48 + c * 16 + lr;
#pragma unroll
      for (int ks = 0; ks < 2; ++ks)
        wf[c][ks] = *(const short8*)&lW[nr * 64 + (((ks << 5) | (lg << 3)) ^ ((nr & 7) << 3))];
    }
#pragma unroll
    for (int m = 0; m < 2; ++m)
#pragma unroll
      for (int c = 0; c < 3; ++c) {
        acc[m][c] = mfma16(af[m][0], wf[c][0], acc[m][c]);
        acc[m][c] = mfma16(af[m][1], wf[c][1], acc[m][c]);
      }
  }

  const int bb  = row0 >> 11;                       // batch (64 | 2048)
  const int tl0 = (row0 & 2047) + wr * 32;
#pragma unroll
  for (int m = 0; m < 2; ++m) {
    const int tl = tl0 + m * 16 + 4 * lg;           // local token for reg r=0
#pragma unroll
    for (int c = 0; c < 3; ++c) {
      const int col = wc * 48 + c * 16 + lr;        // 0..191
      const int hd  = col & 63;
      if (col >= 128) {                             // V -> transposed store
        u16x4 pk;
#pragma unroll
        for (int r = 0; r < 4; ++r) pk[r] = f2bf(acc[m][c][r]);
        *(u16x4*)&vtw[((size_t)bb * 64 + hd) * 2048 + tl] = pk;
      } else {
        u16* dst = (col >= 64) ? kw : qw;
#pragma unroll
        for (int r = 0; r < 4; ++r)
          dst[((size_t)(bb * 2048 + tl + r)) * 64 + hd] = f2bf(acc[m][c][r]);
      }
    }
  }
}

// ---------------------------------------------------------------------------
// Flash attention, causal, scale = 1024^-0.5 = 1/32.
// Wave-task = one 16-row Q strip x one KV half-range (flash-decode split).
// Block: 4 waves = strips {p, 127-p} x halves {0,1}; halves merged via LDS.
// K/V fragments loaded straight from global (L2-resident, 0.5 MB/batch).
// ---------------------------------------------------------------------------
__global__ __launch_bounds__(256) void attn_kernel(
    const u16* __restrict__ qw, const u16* __restrict__ kw,
    const u16* __restrict__ vtw, float* __restrict__ out)
{
  const int tid  = threadIdx.x;
  const int lane = tid & 63;
  const int w    = tid >> 6;
  const int lr   = lane & 15, lg = lane >> 4;
  const int b    = blockIdx.x >> 6;      // batch 0..7
  const int p    = blockIdx.x & 63;      // strip pair id
  const int sid  = w >> 1;               // 0: strip p, 1: strip 127-p
  const int half = w & 1;                // KV half
  const int t    = sid ? (127 - p) : p;  // 16-row strip index 0..127
  const int qrow0 = t * 16;
  const int L    = (t >> 2) + 1;         // # of 64-key KV tiles for this strip
  const int kt0  = half ? (L >> 1) : 0;
  const int kt1  = half ? L : (L >> 1);

  __shared__ u16   plds[4][16 * 64];     // per-wave P staging (XOR-swizzled)
  __shared__ float sO[2][16 * 64];       // half-0 partial O per strip
  __shared__ float sM[2][16];
  __shared__ float sL[2][16];

  const size_t qoff = ((size_t)(b * 2048 + qrow0 + lr)) * 64 + lg * 8;
  const short8 q0 = *(const short8*)(qw + qoff);        // dims  0..31 chunk
  const short8 q1 = *(const short8*)(qw + qoff + 32);   // dims 32..63 chunk

  const f32x4 vzero = {0.f, 0.f, 0.f, 0.f};
  f32x4 o[4];
#pragma unroll
  for (int i = 0; i < 4; ++i) o[i] = vzero;
  float mrow[4] = {-1e30f, -1e30f, -1e30f, -1e30f};
  float lsum[4] = {0.f, 0.f, 0.f, 0.f};

  u16* pw = plds[w];

  for (int kt = kt0; kt < kt1; ++kt) {
    const int kb = kt * 64;
    f32x4 s[4];
#pragma unroll
    for (int c = 0; c < 4; ++c) {
      const u16* kp = kw + ((size_t)(b * 2048 + kb + 16 * c + lr)) * 64 + lg * 8;
      short8 kf0 = *(const short8*)(kp);
      short8 kf1 = *(const short8*)(kp + 32);
      f32x4 z = vzero;
      z = mfma16(q0, kf0, z);
      z = mfma16(q1, kf1, z);
      s[c] = z;
    }
#pragma unroll
    for (int c = 0; c < 4; ++c) s[c] *= 0.03125f;
    if (kt == L - 1) {                    // causal mask (only last tile)
#pragma unroll
      for (int c = 0; c < 4; ++c) {
        const int key = kb + 16 * c + lr;
#pragma unroll
        for (int r = 0; r < 4; ++r) {
          const int qg = qrow0 + 4 * lg + r;
          if (key > qg) s[c][r] = -1e30f;
        }
      }
    }
    float tm[4], rs[4], fr[4];
#pragma unroll
    for (int r = 0; r < 4; ++r)
      tm[r] = fmaxf(fmaxf(s[0][r], s[1][r]), fmaxf(s[2][r], s[3][r]));
#pragma unroll
    for (int msk = 1; msk <= 8; msk <<= 1)
#pragma unroll
      for (int r = 0; r < 4; ++r)
        tm[r] = fmaxf(tm[r], __shfl_xor(tm[r], msk, 64));
#pragma unroll
    for (int r = 0; r < 4; ++r) {
      const float nm = fmaxf(mrow[r], tm[r]);
      fr[r] = __expf(mrow[r] - nm);
      mrow[r] = nm;
    }
#pragma unroll
    for (int c = 0; c < 4; ++c)
#pragma unroll
      for (int r = 0; r < 4; ++r)
        s[c][r] = __expf(s[c][r] - mrow[r]);
#pragma unroll
    for (int r = 0; r < 4; ++r)
      rs[r] = (s[0][r] + s[1][r]) + (s[2][r] + s[3][r]);
#pragma unroll
    for (int msk = 1; msk <= 8; msk <<= 1)
#pragma unroll
      for (int r = 0; r < 4; ++r)
        rs[r] += __shfl_xor(rs[r], msk, 64);
#pragma unroll
    for (int r = 0; r < 4; ++r) lsum[r] = lsum[r] * fr[r] + rs[r];
#pragma unroll
    for (int cd = 0; cd < 4; ++cd)
#pragma unroll
      for (int r = 0; r < 4; ++r) o[cd][r] *= fr[r];

    // P -> LDS (transpose to A-fragment layout), per-wave region, swizzled
#pragma unroll
    for (int c = 0; c < 4; ++c)
#pragma unroll
      for (int r = 0; r < 4; ++r) {
        const int row = 4 * lg + r, col = 16 * c + lr;
        pw[row * 64 + (col ^ ((row & 7) << 3))] = f2bf(s[c][r]);
      }
    const short8 pa0 = *(const short8*)&pw[lr * 64 + ((lg << 3) ^ ((lr & 7) << 3))];
    const short8 pa1 = *(const short8*)&pw[lr * 64 + ((32 | (lg << 3)) ^ ((lr & 7) << 3))];

#pragma unroll
    for (int cd = 0; cd < 4; ++cd) {
      const u16* vp = vtw + ((size_t)(b * 64 + 16 * cd + lr)) * 2048 + kb + lg * 8;
      short8 vf0 = *(const short8*)(vp);
      short8 vf1 = *(const short8*)(vp + 32);
      o[cd] = mfma16(pa0, vf0, o[cd]);
      o[cd] = mfma16(pa1, vf1, o[cd]);
    }
  }

  // merge the two KV halves of each strip
  if (half == 0) {
#pragma unroll
    for (int cd = 0; cd < 4; ++cd)
#pragma unroll
      for (int r = 0; r < 4; ++r)
        sO[sid][(4 * lg + r) * 64 + 16 * cd + lr] = o[cd][r];
    if (lr == 0) {
#pragma unroll
      for (int r = 0; r < 4; ++r) {
        sM[sid][4 * lg + r] = mrow[r];
        sL[sid][4 * lg + r] = lsum[r];
      }
    }
  }
  __syncthreads();
  if (half == 1) {
    float f0[4], f1[4];
#pragma unroll
    for (int r = 0; r < 4; ++r) {
      const float m0 = sM[sid][4 * lg + r];
      const float l0 = sL[sid][4 * lg + r];
      const float mm = fmaxf(m0, mrow[r]);
      const float e0 = __expf(m0 - mm);
      const float e1 = __expf(mrow[r] - mm);
      const float inv = 1.0f / (l0 * e0 + lsum[r] * e1);
      f0[r] = e0 * inv;
      f1[r] = e1 * inv;
    }
#pragma unroll
    for (int cd = 0; cd < 4; ++cd)
#pragma unroll
      for (int r = 0; r < 4; ++r) {
        const int row = 4 * lg + r;
        out[((size_t)(b * 2048 + qrow0 + row)) * 64 + 16 * cd + lr] =
            sO[sid][row * 64 + 16 * cd + lr] * f0[r] + o[cd][r] * f1[r];
      }
  }
}

extern "C" void kernel_launch(void* const* d_in, const int* in_sizes, int n_in,
                              void* d_out, int out_size, void* d_ws, size_t ws_size,
                              hipStream_t stream) {
  // setup_inputs order: x, Wk, Wq, Wv
  const float* x  = (const float*)d_in[0];
  const float* Wk = (const float*)d_in[1];
  const float* Wq = (const float*)d_in[2];
  const float* Wv = (const float*)d_in[3];
  u16* qw  = (u16*)d_ws;                         // [8][2048][64] bf16 = 2 MB
  u16* kw  = qw + (size_t)16384 * 64;            // [8][2048][64] bf16 = 2 MB
  u16* vtw = kw + (size_t)16384 * 64;            // [8][64][2048] bf16 = 2 MB
  float* out = (float*)d_out;

  proj_kernel<<<dim3(256), dim3(512), 0, stream>>>(x, Wq, Wk, Wv, qw, kw, vtw);
  attn_kernel<<<dim3(512), dim3(256), 0, stream>>>(qw, kw, vtw, out);
}

// Round 2
// 67.023 us; speedup vs baseline: 1.1602x; 1.1602x over previous
//
#include <hip/hip_runtime.h>

typedef short short8 __attribute__((ext_vector_type(8)));
typedef float f32x4 __attribute__((ext_vector_type(4)));
typedef unsigned int u32;
typedef unsigned short u16;

union PackU { u32 u[4]; short8 s8; };

__device__ __forceinline__ u16 f2bf(float f) {
  unsigned u = __builtin_bit_cast(unsigned, f);
  u = (u + 0x7FFFu + ((u >> 16) & 1u)) >> 16;
  return (u16)u;
}

__device__ __forceinline__ u32 cvt_pk_bf16(float lo, float hi) {
  u32 r;
  asm("v_cvt_pk_bf16_f32 %0, %1, %2" : "=v"(r) : "v"(lo), "v"(hi));
  return r;
}

__device__ __forceinline__ f32x4 mfma16(short8 a, short8 b, f32x4 c) {
  return __builtin_amdgcn_mfma_f32_16x16x32_bf16(a, b, c, 0, 0, 0);
}

// scale for Wq: (1/sqrt(1024)) * log2(e)  -> scores come out in log2 domain
#define QSCALE 0.04508422619125366f

// ---------------------------------------------------------------------------
// W conversion: wcat[192][1024] bf16. rows 0..63 = Wq*QSCALE, 64..127 = Wk,
// 128..191 = Wv.  grid 96 x 256, 8 elems/thread.
// ---------------------------------------------------------------------------
__global__ __launch_bounds__(256) void wconv_kernel(
    const float* __restrict__ Wk, const float* __restrict__ Wq,
    const float* __restrict__ Wv, u16* __restrict__ wcat)
{
  const int t = blockIdx.x * 256 + threadIdx.x;   // 24576 threads
  const int row = t >> 7;
  const int col = (t & 127) * 8;
  const float* src;
  float scale = 1.0f;
  if (row < 64)       { src = Wq + (size_t)row * 1024;        scale = QSCALE; }
  else if (row < 128) { src = Wk + (size_t)(row - 64) * 1024; }
  else                { src = Wv + (size_t)(row - 128) * 1024; }
  float4 a = *(const float4*)(src + col);
  float4 b = *(const float4*)(src + col + 4);
  PackU p;
  p.u[0] = cvt_pk_bf16(a.x * scale, a.y * scale);
  p.u[1] = cvt_pk_bf16(a.z * scale, a.w * scale);
  p.u[2] = cvt_pk_bf16(b.x * scale, b.y * scale);
  p.u[3] = cvt_pk_bf16(b.z * scale, b.w * scale);
  *(short8*)&wcat[(size_t)row * 1024 + col] = p.s8;
}

// ---------------------------------------------------------------------------
// Projection: 512 blocks x 256 thr (4 waves). Block = 32 rows x 192 cols.
// Wave = 32 rows x 48 cols (2 row-tiles x 3 col-tiles).
// W-slice [192][64] bf16 double-buffered in LDS (one barrier/step).
// x loaded direct to regs (fp32), packed with v_cvt_pk_bf16_f32.
// Outputs: qw,kw [8][2048][64] bf16; vtw [8][64][2048] bf16 in PERMUTED
// key order: within each 32-token block, token t stored at
// (lg<<3)|(sub<<2)|r  where lg=(t>>2)&3, sub=(t>>4)&1, r=t&3.
// ---------------------------------------------------------------------------
__global__ __launch_bounds__(256, 2) void proj_kernel(
    const float* __restrict__ x, const u16* __restrict__ wcat,
    u16* __restrict__ qw, u16* __restrict__ kw, u16* __restrict__ vtw)
{
  const int tid  = threadIdx.x;
  const int lane = tid & 63;
  const int w    = tid >> 6;
  const int lr   = lane & 15, lg = lane >> 4;
  const int row0 = blockIdx.x * 32;
  const int n0   = w * 48;

  __shared__ u16 lW[2][192 * 64];   // 2 x 24KB

  const f32x4 vzero = {0.f, 0.f, 0.f, 0.f};
  f32x4 acc[2][3];
#pragma unroll
  for (int m = 0; m < 2; ++m)
#pragma unroll
    for (int c = 0; c < 3; ++c) acc[m][c] = vzero;

  // staging geometry: 1536 16B-chunks, 6 per thread
  const int sr0 = (tid) >> 3;          // row for i=0 chunk (grows by 32/i)
  const int sc0 = (tid & 7) * 8;

  short8 wcur[6];
#pragma unroll
  for (int i = 0; i < 6; ++i) {
    const int r = sr0 + i * 32;
    wcur[i] = *(const short8*)&wcat[(size_t)r * 1024 + sc0];
  }
#pragma unroll
  for (int i = 0; i < 6; ++i) {
    const int r = sr0 + i * 32;
    *(short8*)&lW[0][(r * 64 + sc0) ^ ((r & 7) << 3)] = wcur[i];
  }
  __syncthreads();

  for (int s = 0; s < 16; ++s) {
    const int k0 = s * 64;
    const int cur = s & 1;
    if (s < 15) {
#pragma unroll
      for (int i = 0; i < 6; ++i) {
        const int r = sr0 + i * 32;
        wcur[i] = *(const short8*)&wcat[(size_t)r * 1024 + k0 + 64 + sc0];
      }
    }
    // A: direct global fp32 -> bf16 frags
    short8 af[2][2];
#pragma unroll
    for (int m = 0; m < 2; ++m) {
      const float* xp = x + (size_t)(row0 + 16 * m + lr) * 1024 + k0 + lg * 8;
#pragma unroll
      for (int ks = 0; ks < 2; ++ks) {
        float4 a = *(const float4*)(xp + ks * 32);
        float4 b = *(const float4*)(xp + ks * 32 + 4);
        PackU p;
        p.u[0] = cvt_pk_bf16(a.x, a.y);
        p.u[1] = cvt_pk_bf16(a.z, a.w);
        p.u[2] = cvt_pk_bf16(b.x, b.y);
        p.u[3] = cvt_pk_bf16(b.z, b.w);
        af[m][ks] = p.s8;
      }
    }
#pragma unroll
    for (int c = 0; c < 3; ++c) {
      const int n = n0 + 16 * c + lr;
      const short8 wf0 = *(const short8*)&lW[cur][(n * 64 + lg * 8) ^ ((n & 7) << 3)];
      const short8 wf1 = *(const short8*)&lW[cur][(n * 64 + 32 + lg * 8) ^ ((n & 7) << 3)];
#pragma unroll
      for (int m = 0; m < 2; ++m) {
        acc[m][c] = mfma16(af[m][0], wf0, acc[m][c]);
        acc[m][c] = mfma16(af[m][1], wf1, acc[m][c]);
      }
    }
    if (s < 15) {
#pragma unroll
      for (int i = 0; i < 6; ++i) {
        const int r = sr0 + i * 32;
        *(short8*)&lW[cur ^ 1][(r * 64 + sc0) ^ ((r & 7) << 3)] = wcur[i];
      }
    }
    __syncthreads();
  }

  const int bb = row0 >> 11;
  const int tb = row0 & 2047;
#pragma unroll
  for (int m = 0; m < 2; ++m) {
    const int tl0 = tb + 16 * m + 4 * lg;
#pragma unroll
    for (int c = 0; c < 3; ++c) {
      const int n  = n0 + 16 * c + lr;
      const int hd = n & 63;
      if (n < 128) {
        u16* dst = (n < 64) ? qw : kw;
#pragma unroll
        for (int r = 0; r < 4; ++r)
          dst[((size_t)(bb * 2048 + tl0 + r)) * 64 + hd] = f2bf(acc[m][c][r]);
      } else {
        const int posb = (tl0 & ~31) | (((tl0 >> 2) & 3) << 3) | (((tl0 >> 4) & 1) << 2);
        u32* dst = (u32*)&vtw[((size_t)(bb * 64 + hd)) * 2048 + posb];
        dst[0] = cvt_pk_bf16(acc[m][c][0], acc[m][c][1]);
        dst[1] = cvt_pk_bf16(acc[m][c][2], acc[m][c][3]);
      }
    }
  }
}

// ---------------------------------------------------------------------------
// Attention partials. grid = 8 batches x 80 (group,chunk) blocks, 256 thr.
// Block = q-group j (64 rows = 4 waves x 16-row strips), KV chunk of <=8
// 64-key tiles staged in LDS (dbuf, XOR-swizzled), shared by the 4 waves.
// Swapped QK (A=K, B=Q): lane holds S[key=16c+4lg+r][q=lr]. Static-max
// softmax: P = exp2(S) (Wq pre-scaled by log2e/32), per-lane scalar lsum.
// PV: A=V(perm layout), B=P packed lane-locally. Chunked groups write
// unnormalized partials; single-chunk groups (j<8) write out directly.
// ---------------------------------------------------------------------------
__global__ __launch_bounds__(256, 2) void attn_kernel(
    const u16* __restrict__ qw, const u16* __restrict__ kw,
    const u16* __restrict__ vtw, float* __restrict__ out,
    float* __restrict__ Opart, float* __restrict__ lpart)
{
  const int tid  = threadIdx.x;
  const int lane = tid & 63;
  const int sid  = tid >> 6;           // strip 0..3
  const int lr   = lane & 15, lg = lane >> 4;
  const int bid  = blockIdx.x;
  const int b    = bid / 80;
  const int g    = bid % 80;

  int j, ch, nch;
  if (g < 8)       { j = g;                ch = 0;          nch = 1; }
  else if (g < 24) { int u = g - 8;  j = 8  + (u >> 1); ch = u & 1;  nch = 2; }
  else if (g < 48) { int u = g - 24; j = 16 + u / 3;    ch = u % 3;  nch = 3; }
  else             { int u = g - 48; j = 24 + (u >> 2); ch = u & 3;  nch = 4; }
  const int kt0 = ch * 8;
  const int kt1 = (kt0 + 8 < j + 1) ? (kt0 + 8) : (j + 1);
  const int q0r = j * 64 + sid * 16;

  __shared__ u16 lK[2][64 * 64];
  __shared__ u16 lV[2][64 * 64];

  const size_t qoff = ((size_t)(b * 2048 + q0r + lr)) * 64 + lg * 8;
  const short8 qa = *(const short8*)(qw + qoff);
  const short8 qb = *(const short8*)(qw + qoff + 32);

  const f32x4 vzero = {0.f, 0.f, 0.f, 0.f};
  f32x4 o[4];
#pragma unroll
  for (int i = 0; i < 4; ++i) o[i] = vzero;
  float lsum = 0.f;

  // staging geometry: 512 chunks per matrix, 2 per thread
  const int sr0 = tid >> 3;            // 0..31 (i=1 adds 32)
  const int sc0 = (tid & 7) * 8;
  const int la0 = (sr0 * 64 + sc0) ^ ((sr0 & 7) << 3);

  short8 kst[2], vst[2];
  {
    const int kb = kt0 * 64;
#pragma unroll
    for (int i = 0; i < 2; ++i) {
      const int r = sr0 + i * 32;
      kst[i] = *(const short8*)(kw  + ((size_t)(b * 2048 + kb + r)) * 64 + sc0);
      vst[i] = *(const short8*)(vtw + ((size_t)(b * 64 + r)) * 2048 + kb + sc0);
    }
#pragma unroll
    for (int i = 0; i < 2; ++i) {
      *(short8*)&lK[0][la0 + i * 2048] = kst[i];
      *(short8*)&lV[0][la0 + i * 2048] = vst[i];
    }
  }
  __syncthreads();

  for (int kt = kt0; kt < kt1; ++kt) {
    const int cur = (kt - kt0) & 1;
    if (kt + 1 < kt1) {
      const int kb = (kt + 1) * 64;
#pragma unroll
      for (int i = 0; i < 2; ++i) {
        const int r = sr0 + i * 32;
        kst[i] = *(const short8*)(kw  + ((size_t)(b * 2048 + kb + r)) * 64 + sc0);
        vst[i] = *(const short8*)(vtw + ((size_t)(b * 64 + r)) * 2048 + kb + sc0);
      }
    }
    // QK^T (swapped): s4[c][r] = S[key = 64kt+16c+4lg+r][q = q0r+lr]
    f32x4 s4[4];
#pragma unroll
    for (int c = 0; c < 4; ++c) {
      const int row = 16 * c + lr;
      const short8 kf0 = *(const short8*)&lK[cur][(row * 64 + lg * 8) ^ ((row & 7) << 3)];
      const short8 kf1 = *(const short8*)&lK[cur][(row * 64 + 32 + lg * 8) ^ ((row & 7) << 3)];
      f32x4 z = vzero;
      z = mfma16(kf0, qa, z);
      z = mfma16(kf1, qb, z);
      s4[c] = z;
    }
    if (kt == j) {   // causal mask on the diagonal tile
#pragma unroll
      for (int c = 0; c < 4; ++c)
#pragma unroll
        for (int r = 0; r < 4; ++r)
          if (16 * c + 4 * lg + r > sid * 16 + lr) s4[c][r] = -1e30f;
    }
    // exp2 + lane-local row-sum accumulation
#pragma unroll
    for (int c = 0; c < 4; ++c)
#pragma unroll
      for (int r = 0; r < 4; ++r) {
        const float e = __builtin_amdgcn_exp2f(s4[c][r]);
        s4[c][r] = e;
        lsum += e;
      }
    // pack P lane-locally: pb0 = keys of c=0,1 ; pb1 = keys of c=2,3
    PackU p0, p1;
    p0.u[0] = cvt_pk_bf16(s4[0][0], s4[0][1]);
    p0.u[1] = cvt_pk_bf16(s4[0][2], s4[0][3]);
    p0.u[2] = cvt_pk_bf16(s4[1][0], s4[1][1]);
    p0.u[3] = cvt_pk_bf16(s4[1][2], s4[1][3]);
    p1.u[0] = cvt_pk_bf16(s4[2][0], s4[2][1]);
    p1.u[1] = cvt_pk_bf16(s4[2][2], s4[2][3]);
    p1.u[2] = cvt_pk_bf16(s4[3][0], s4[3][1]);
    p1.u[3] = cvt_pk_bf16(s4[3][2], s4[3][3]);
    const short8 pb0 = p0.s8, pb1 = p1.s8;
    // PV: o[cd] over d = 16cd+4lg+r
#pragma unroll
    for (int cd = 0; cd < 4; ++cd) {
      const int row = 16 * cd + lr;
      const short8 vf0 = *(const short8*)&lV[cur][(row * 64 + lg * 8) ^ ((row & 7) << 3)];
      const short8 vf1 = *(const short8*)&lV[cur][(row * 64 + 32 + lg * 8) ^ ((row & 7) << 3)];
      o[cd] = mfma16(vf0, pb0, o[cd]);
      o[cd] = mfma16(vf1, pb1, o[cd]);
    }
    if (kt + 1 < kt1) {
#pragma unroll
      for (int i = 0; i < 2; ++i) {
        *(short8*)&lK[cur ^ 1][la0 + i * 2048] = kst[i];
        *(short8*)&lV[cur ^ 1][la0 + i * 2048] = vst[i];
      }
      __syncthreads();
    }
  }

  lsum += __shfl_xor(lsum, 16, 64);
  lsum += __shfl_xor(lsum, 32, 64);

  if (nch == 1) {
    const float inv = 1.0f / lsum;
    float* op = out + ((size_t)(b * 2048 + q0r + lr)) * 64;
#pragma unroll
    for (int cd = 0; cd < 4; ++cd) {
      f32x4 v = o[cd] * inv;
      *(f32x4*)(op + 16 * cd + 4 * lg) = v;
    }
  } else {
    int pb;
    if (j < 16)      pb = 2 * (j - 8);
    else if (j < 24) pb = 16 + 3 * (j - 16);
    else             pb = 40 + 4 * (j - 24);
    const int pidx = b * 72 + pb + ch;
    float* op = Opart + ((size_t)(pidx * 64) + sid * 16 + lr) * 64;
#pragma unroll
    for (int cd = 0; cd < 4; ++cd)
      *(f32x4*)(op + 16 * cd + 4 * lg) = o[cd];
    if (lg == 0) lpart[pidx * 64 + sid * 16 + lr] = lsum;
  }
}

// ---------------------------------------------------------------------------
// Merge partials for chunked groups (j >= 8). 768 blocks x 256 thr.
// thread -> (merged q-row, 4-wide d quad); out = sum(Opart)/sum(l).
// ---------------------------------------------------------------------------
__global__ __launch_bounds__(256) void merge_kernel(
    const float* __restrict__ Opart, const float* __restrict__ lpart,
    float* __restrict__ out)
{
  const int t = blockIdx.x * 256 + threadIdx.x;
  const int ridx = t >> 4;           // 0..12287
  const int dq = (t & 15) * 4;
  const int b = ridx / 1536;
  const int r2 = ridx % 1536;
  const int jj = r2 >> 6;            // 0..23 -> j = jj+8
  const int ql = r2 & 63;
  int pb, nch;
  if (jj < 8)       { pb = 2 * jj;            nch = 2; }
  else if (jj < 16) { pb = 16 + 3 * (jj - 8); nch = 3; }
  else              { pb = 40 + 4 * (jj - 16); nch = 4; }
  const int base = b * 72 + pb;
  f32x4 acc = {0.f, 0.f, 0.f, 0.f};
  float l = 0.f;
  for (int c = 0; c < nch; ++c) {
    acc += *(const f32x4*)(Opart + (((size_t)(base + c) * 64 + ql) * 64 + dq));
    l += lpart[(base + c) * 64 + ql];
  }
  const float inv = 1.0f / l;
  *(f32x4*)&out[((size_t)(b * 2048 + (jj + 8) * 64 + ql)) * 64 + dq] = acc * inv;
}

extern "C" void kernel_launch(void* const* d_in, const int* in_sizes, int n_in,
                              void* d_out, int out_size, void* d_ws, size_t ws_size,
                              hipStream_t stream) {
  // setup_inputs order: x, Wk, Wq, Wv
  const float* x  = (const float*)d_in[0];
  const float* Wk = (const float*)d_in[1];
  const float* Wq = (const float*)d_in[2];
  const float* Wv = (const float*)d_in[3];

  u16* wcat = (u16*)d_ws;                        // 192*1024       = 196608
  u16* qw   = wcat + 196608;                     // 16384*64
  u16* kw   = qw + 1048576;
  u16* vtw  = kw + 1048576;
  float* Opart = (float*)(vtw + 1048576);        // 576*64*64 f32
  float* lpart = Opart + 2359296;                // 576*64 f32
  float* out = (float*)d_out;

  wconv_kernel<<<dim3(96),  dim3(256), 0, stream>>>(Wk, Wq, Wv, wcat);
  proj_kernel <<<dim3(512), dim3(256), 0, stream>>>(x, wcat, qw, kw, vtw);
  attn_kernel <<<dim3(640), dim3(256), 0, stream>>>(qw, kw, vtw, out, Opart, lpart);
  merge_kernel<<<dim3(768), dim3(256), 0, stream>>>(Opart, lpart, out);
}